// Round 5
// baseline (166.807 us; speedup 1.0000x reference)
//
#include <hip/hip_runtime.h>
#include <hip/hip_bf16.h>

constexpr int Dd   = 512;
constexpr int Nn   = 1024;
constexpr int Ttok = 16384;              // B*L
constexpr float DECAYc = 0.99f;
constexpr float MARGIN = 10.0f;
constexpr int CH = 16;                   // tokens per dw chunk

typedef short bf16x8 __attribute__((ext_vector_type(8)));
typedef float f32x4  __attribute__((ext_vector_type(4)));
typedef unsigned short us8v __attribute__((ext_vector_type(8)));

__device__ inline unsigned short f2bf(float f) {       // round-to-nearest-even
  unsigned int b = __float_as_uint(f);
  return (unsigned short)((b + 0x7FFFu + ((b >> 16) & 1u)) >> 16);
}
__device__ inline float bf2f(unsigned short u) {
  return __uint_as_float(((unsigned int)u) << 16);
}

// ------------------------------------------- codebook -> bf16, plus csq[n]
__global__ __launch_bounds__(64) void k_prep_cb(const float* __restrict__ cb,
                                                unsigned short* __restrict__ cbh,
                                                float* __restrict__ csq) {
  const int n = blockIdx.x, l = threadIdx.x;
  const float4* r = (const float4*)(cb + (size_t)n * Dd);
  float4 a = r[l], b = r[l + 64];
  float ss = a.x*a.x + a.y*a.y + a.z*a.z + a.w*a.w
           + b.x*b.x + b.y*b.y + b.z*b.z + b.w*b.w;
  ushort4 ua, ub;
  ua.x = f2bf(a.x); ua.y = f2bf(a.y); ua.z = f2bf(a.z); ua.w = f2bf(a.w);
  ub.x = f2bf(b.x); ub.y = f2bf(b.y); ub.z = f2bf(b.z); ub.w = f2bf(b.w);
  ((ushort4*)(cbh + (size_t)n * Dd))[l]      = ua;
  ((ushort4*)(cbh + (size_t)n * Dd))[l + 64] = ub;
#pragma unroll
  for (int o = 32; o; o >>= 1) ss += __shfl_down(ss, o);
  if (l == 0) csq[n] = ss;
}

// ---------------------- MFMA coarse-score GEMM: S[t][n] = csq[n] - 2*x.c
// LDS tiles XOR-swizzled (chunk' = chunk ^ (row&7), 16B chunks) to kill the
// 16-way ds_read_b128 conflicts. A: swizzle via pre-swizzled GLOBAL source
// (global_load_lds dest must stay linear); B: reg-staged, swizzled ds_write.
// B-tile for kc+1 is prefetched right after the post-staging barrier so its
// global latency hides under the MFMA phase.
__global__ __launch_bounds__(256) void k_gemm_scores(
    const unsigned short* __restrict__ cbh, const float* __restrict__ x,
    const float* __restrict__ csq, unsigned short* __restrict__ S) {
  __shared__ unsigned short As[128 * 64];    // codes   [row][64], 16B chunks swizzled
  __shared__ unsigned short Bs[128 * 64];    // tokens
  const int tid = threadIdx.x;
  const int w = tid >> 6, l = tid & 63;
  const int b = blockIdx.x;
  const int s = (b & 7) * 128 + (b >> 3);    // XCD-aware bijective swizzle
  const int cm = s & 7;        // code-block  (M)
  const int tn = s >> 3;       // token-block (N)
  const int wr = w >> 1, wc = w & 1;

  const int srow = tid >> 3;                 // 0..31 staging row base
  const int xorw = (tid >> 3) & 7;           // row&7 of this thread's staged rows
  const int scolA = ((tid & 7) ^ xorw) * 8;  // A: swizzled global source chunk
  const int scolB = (tid & 7) * 8;           // B: linear global chunk
  const int wcolB = ((tid & 7) ^ xorw) * 8;  // B: swizzled LDS write chunk

  f32x4 acc[4][4] = {};

  const unsigned short* gA0 = cbh + (size_t)(cm * 128) * Dd;
  const float*          gB0 = x   + (size_t)(tn * 128) * Dd;

  us8v bq[4];
#define LOADB(KC) do {                                                        \
    const int k0_ = (KC) * 64;                                                \
    _Pragma("unroll")                                                         \
    for (int p = 0; p < 4; ++p) {                                             \
      const float* gb = gB0 + (size_t)(p * 32 + srow) * Dd + k0_ + scolB;     \
      float4 v0 = *(const float4*)gb;                                         \
      float4 v1 = *(const float4*)(gb + 4);                                   \
      us8v o;                                                                 \
      o[0]=f2bf(v0.x); o[1]=f2bf(v0.y); o[2]=f2bf(v0.z); o[3]=f2bf(v0.w);     \
      o[4]=f2bf(v1.x); o[5]=f2bf(v1.y); o[6]=f2bf(v1.z); o[7]=f2bf(v1.w);     \
      bq[p] = o;                                                              \
    }                                                                         \
  } while (0)

  LOADB(0);

  for (int kc = 0; kc < Dd / 64; ++kc) {
    const int k0 = kc * 64;
    __syncthreads();                      // previous tile fully consumed
    // A: codebook bf16, direct global->LDS, source pre-swizzled
#pragma unroll
    for (int c = 0; c < 4; ++c) {
      const unsigned short* ga = gA0 + (size_t)(c * 32 + srow) * Dd + k0 + scolA;
      char* la = (char*)As + c * 4096 + w * 1024;   // wave-uniform base, linear dest
      __builtin_amdgcn_global_load_lds((const __attribute__((address_space(1))) void*)ga,
                                       (__attribute__((address_space(3))) void*)la, 16, 0, 0);
    }
    // B: write prefetched+converted regs to swizzled LDS slots
#pragma unroll
    for (int p = 0; p < 4; ++p)
      *(us8v*)&Bs[(p * 32 + srow) * 64 + wcolB] = bq[p];
    __syncthreads();                      // drains vmcnt+lgkmcnt
    if (kc + 1 < Dd / 64) LOADB(kc + 1);  // prefetch: latency hides under MFMA
#pragma unroll
    for (int ks = 0; ks < 2; ++ks) {
      const int ra = l & 15;
      const int rx = l & 7;               // row&7 of the fragment rows
      const int kbs = ((ks * 4 + (l >> 4)) ^ rx) * 8;   // swizzled read chunk
      bf16x8 af[4], bfr[4];
#pragma unroll
      for (int m = 0; m < 4; ++m)
        af[m] = *(const bf16x8*)&As[(wr * 64 + m * 16 + ra) * 64 + kbs];
#pragma unroll
      for (int n = 0; n < 4; ++n)
        bfr[n] = *(const bf16x8*)&Bs[(wc * 64 + n * 16 + ra) * 64 + kbs];
#pragma unroll
      for (int m = 0; m < 4; ++m)
#pragma unroll
        for (int n = 0; n < 4; ++n)
          acc[m][n] = __builtin_amdgcn_mfma_f32_16x16x32_bf16(af[m], bfr[n], acc[m][n], 0, 0, 0);
    }
  }
#undef LOADB

  const int code0 = cm * 128 + wr * 64 + (l >> 4) * 4;
  const int tok0  = tn * 128 + wc * 64 + (l & 15);
#pragma unroll
  for (int m = 0; m < 4; ++m) {
    const int cd = code0 + m * 16;
    float4 cs = *(const float4*)&csq[cd];
#pragma unroll
    for (int n = 0; n < 4; ++n) {
      const int tk = tok0 + n * 16;
      ushort4 o;
      o.x = f2bf(cs.x - 2.0f * acc[m][n][0]);
      o.y = f2bf(cs.y - 2.0f * acc[m][n][1]);
      o.z = f2bf(cs.z - 2.0f * acc[m][n][2]);
      o.w = f2bf(cs.w - 2.0f * acc[m][n][3]);
      *(ushort4*)(S + (size_t)tk * Nn + cd) = o;
    }
  }
}

// ------------- per-token: coarse min over 1024, candidates, exact rescore
__global__ __launch_bounds__(256) void k_scan(
    const unsigned short* __restrict__ S, const float* __restrict__ x,
    const float* __restrict__ cb, const float* __restrict__ csq,
    int* __restrict__ idxb, float* __restrict__ idxf, float* __restrict__ hist) {
  __shared__ int candn[4][32];
  __shared__ int ccnt[4];
  const int tid = threadIdx.x, wid = tid >> 6, l = tid & 63;
  const int t = blockIdx.x * 4 + wid;

  const unsigned short* row = S + (size_t)t * Nn;
  us8v c0 = *(const us8v*)(row + l * 8);
  us8v c1 = *(const us8v*)(row + 512 + l * 8);
  float f0[8], f1[8];
  float minv = 3.4e38f; int mini = 0;
#pragma unroll
  for (int j = 0; j < 8; ++j) {
    f0[j] = bf2f(c0[j]);
    if (f0[j] < minv) { minv = f0[j]; mini = l * 8 + j; }
  }
#pragma unroll
  for (int j = 0; j < 8; ++j) {
    f1[j] = bf2f(c1[j]);
    if (f1[j] < minv) { minv = f1[j]; mini = 512 + l * 8 + j; }
  }
#pragma unroll
  for (int o = 1; o < 64; o <<= 1) {
    float ov = __shfl_xor(minv, o); int oi = __shfl_xor(mini, o);
    if (ov < minv || (ov == minv && oi < mini)) { minv = ov; mini = oi; }
  }
  if (l == 0) ccnt[wid] = 0;
  const float thr = minv + MARGIN;
#pragma unroll
  for (int j = 0; j < 8; ++j)
    if (f0[j] <= thr) { int p = atomicAdd(&ccnt[wid], 1); if (p < 32) candn[wid][p] = l * 8 + j; }
#pragma unroll
  for (int j = 0; j < 8; ++j)
    if (f1[j] <= thr) { int p = atomicAdd(&ccnt[wid], 1); if (p < 32) candn[wid][p] = 512 + l * 8 + j; }
  int nc = ccnt[wid]; if (nc > 32) nc = 32;

  int besti;
  if (nc == 1) {
    besti = candn[wid][0];
  } else {
    float bestv = 3.4e38f; besti = 0x7fffffff;
    const float4* xr = (const float4*)(x + (size_t)t * Dd);
    float4 xa = xr[l * 2], xb = xr[l * 2 + 1];
    for (int c = 0; c < nc; ++c) {
      int n = candn[wid][c];
      const float4* cr = (const float4*)(cb + (size_t)n * Dd);
      float4 ca = cr[l * 2], cb4 = cr[l * 2 + 1];
      float p = xa.x*ca.x + xa.y*ca.y + xa.z*ca.z + xa.w*ca.w
              + xb.x*cb4.x + xb.y*cb4.y + xb.z*cb4.z + xb.w*cb4.w;
#pragma unroll
      for (int o = 32; o; o >>= 1) p += __shfl_xor(p, o);
      float sc = csq[n] - 2.0f * p;
      if (sc < bestv || (sc == bestv && n < besti)) { bestv = sc; besti = n; }
    }
  }
  if (l == 0) {
    idxb[t] = besti;
    idxf[t] = (float)besti;
    atomicAdd(&hist[besti], 1.0f);
  }
}

// ----------------- prefix sum of histogram (1 block, 256 thr, wave scan)
__global__ __launch_bounds__(256) void k_offsets(const float* __restrict__ hist,
                                                 int* __restrict__ offs,
                                                 int* __restrict__ cursor) {
  __shared__ int wsum[4];
  const int tid = threadIdx.x, l = tid & 63, wd = tid >> 6;
  const int base = tid * 4;
  int c0 = (int)hist[base], c1 = (int)hist[base + 1],
      c2 = (int)hist[base + 2], c3 = (int)hist[base + 3];
  int sum = c0 + c1 + c2 + c3;
  int sc = sum;
#pragma unroll
  for (int o = 1; o < 64; o <<= 1) { int v = __shfl_up(sc, o); if (l >= o) sc += v; }
  if (l == 63) wsum[wd] = sc;
  __syncthreads();
  int wbase = 0;
  for (int i = 0; i < wd; ++i) wbase += wsum[i];
  int e = wbase + sc - sum;                 // exclusive prefix for this group
  offs[base] = e;     cursor[base] = e;
  offs[base+1] = e + c0; cursor[base+1] = e + c0;
  offs[base+2] = e + c0 + c1; cursor[base+2] = e + c0 + c1;
  offs[base+3] = e + c0 + c1 + c2; cursor[base+3] = e + c0 + c1 + c2;
}

// -------------------------------- bucket tokens by index (code-sorted order)
__global__ __launch_bounds__(256) void k_scatter(const int* __restrict__ idxb,
                                                 int* __restrict__ cursor,
                                                 int* __restrict__ bucket,
                                                 int* __restrict__ bcode) {
  int t = blockIdx.x * 256 + threadIdx.x;
  if (t < Ttok) {
    int n = idxb[t];
    int p = atomicAdd(&cursor[n], 1);
    bucket[p] = t;
    bcode[p] = n;
  }
}

// ------- load-balanced segmented sum: dw[n][d] += x rows of chunk segments
__global__ __launch_bounds__(512) void k_dw_part(
    const float* __restrict__ x, const int* __restrict__ bucket,
    const int* __restrict__ bcode, float* __restrict__ dw) {
  __shared__ int sh_t[CH], sh_n[CH];
  const int tid = threadIdx.x;
  const int p0 = blockIdx.x * CH;
  if (tid < CH) { sh_t[tid] = bucket[p0 + tid]; sh_n[tid] = bcode[p0 + tid]; }
  __syncthreads();
  float v[CH];
#pragma unroll
  for (int j = 0; j < CH; ++j)
    v[j] = x[(size_t)sh_t[j] * Dd + tid];    // 16 independent loads in flight
  float acc = v[0]; int cur = sh_n[0];       // segmented accumulate (uniform branch)
#pragma unroll
  for (int j = 1; j < CH; ++j) {
    int n = sh_n[j];
    if (n != cur) { atomicAdd(&dw[(size_t)cur * Dd + tid], acc); acc = 0.f; cur = n; }
    acc += v[j];
  }
  atomicAdd(&dw[(size_t)cur * Dd + tid], acc);
}

// -------- codebook_new = (decay*ema + (1-decay)*dw) / (decay*counts + (1-decay)*hist)
__global__ __launch_bounds__(256) void finalize_cb(
    const float* __restrict__ ema, const float* __restrict__ dw,
    const float* __restrict__ counts, const float* __restrict__ hist,
    float* __restrict__ cbnew) {
  int e4 = blockIdx.x * 256 + threadIdx.x;   // float4 index
  int n = e4 >> 7;
  float cnt = DECAYc * counts[n] + (1.0f - DECAYc) * hist[n];
  float inv = 1.0f / cnt;
  float4 e = ((const float4*)ema)[e4];
  float4 d = ((const float4*)dw)[e4];
  float4 o;
  o.x = (DECAYc * e.x + (1.0f - DECAYc) * d.x) * inv;
  o.y = (DECAYc * e.y + (1.0f - DECAYc) * d.y) * inv;
  o.z = (DECAYc * e.z + (1.0f - DECAYc) * d.z) * inv;
  o.w = (DECAYc * e.w + (1.0f - DECAYc) * d.w) * inv;
  ((float4*)cbnew)[e4] = o;
}

// ------- quantized = gather(cbnew, idx); loss reduce; last block finalizes
__global__ __launch_bounds__(256) void quant_loss(
    const float* __restrict__ x, const float* __restrict__ cbnew,
    const int* __restrict__ idx, float* __restrict__ out_q,
    float* __restrict__ loss, int* __restrict__ counter,
    float* __restrict__ out_loss) {
  float part = 0.f;
  const int total4 = Ttok * Dd / 4;
  for (int e4 = blockIdx.x * 256 + threadIdx.x; e4 < total4;
       e4 += gridDim.x * 256) {
    int t = e4 >> 7, d4 = e4 & 127;
    int n = idx[t];
    float4 q = ((const float4*)(cbnew + (size_t)n * Dd))[d4];
    float4 xv = ((const float4*)x)[e4];
    ((float4*)out_q)[e4] = q;
    float dx = xv.x - q.x, dy = xv.y - q.y, dz = xv.z - q.z, dw_ = xv.w - q.w;
    part += dx*dx + dy*dy + dz*dz + dw_*dw_;
  }
  __shared__ float red[4];
#pragma unroll
  for (int o = 32; o; o >>= 1) part += __shfl_down(part, o);
  int wid = threadIdx.x >> 6, lane = threadIdx.x & 63;
  if (lane == 0) red[wid] = part;
  __syncthreads();
  if (threadIdx.x == 0) {
    atomicAdd(loss, red[0] + red[1] + red[2] + red[3]);
    __threadfence();
    int prev = atomicAdd(counter, 1);
    if (prev == (int)gridDim.x - 1)
      *out_loss = *loss * (0.5f / (float)((size_t)Ttok * Dd));
  }
}

// ---------------------------------------------------------------- launch
extern "C" void kernel_launch(void* const* d_in, const int* in_sizes, int n_in,
                              void* d_out, int out_size, void* d_ws, size_t ws_size,
                              hipStream_t stream) {
  const float* x      = (const float*)d_in[0];
  const float* cb     = (const float*)d_in[1];
  const float* ema    = (const float*)d_in[2];
  const float* counts = (const float*)d_in[3];

  float* out      = (float*)d_out;
  float* q_out    = out;
  float* loss_out = out + (size_t)Ttok * Dd;
  float* idxf_out = loss_out + 1;
  // coarse score matrix S (bf16 [16384][1024] = 33.5 MB) aliases q_out;
  // fully consumed by k_scan before quant_loss overwrites it.
  unsigned short* S = (unsigned short*)q_out;

  // workspace layout (float offsets)
  float* ws = (float*)d_ws;
  unsigned short* cbh = (unsigned short*)ws;           // [0, 262144)  bf16 cb
  float* dw      = ws + 262144;                        // 524288 (zeroed)
  float* hist    = ws + 786432;                        // 1024   (zeroed)
  float* loss    = ws + 787456;                        // 1      (zeroed)
  int*   counter = (int*)(ws + 787457);                // 1      (zeroed)
  float* csq     = ws + 787460;                        // 1024
  int*   offs    = (int*)(ws + 788484);                // 1024
  int*   cursor  = (int*)(ws + 789508);                // 1024
  int*   bucket  = (int*)(ws + 790532);                // 16384
  int*   bcode   = (int*)(ws + 806916);                // 16384
  int*   idxb    = (int*)(ws + 823300);                // 16384
  float* cbnew   = ws + 839684;                        // 524288 -> ends 1363972
  // total 1,363,972 floats = 5.46 MB

  // zero dw + hist + loss + counter (contiguous) every call
  hipMemsetAsync(dw, 0, (size_t)525316 * sizeof(float), stream);

  k_prep_cb<<<Nn, 64, 0, stream>>>(cb, cbh, csq);
  k_gemm_scores<<<(Nn / 128) * (Ttok / 128), 256, 0, stream>>>(cbh, x, csq, S);
  k_scan<<<Ttok / 4, 256, 0, stream>>>(S, x, cb, csq, idxb, idxf_out, hist);
  k_offsets<<<1, 256, 0, stream>>>(hist, offs, cursor);
  k_scatter<<<Ttok / 256, 256, 0, stream>>>(idxb, cursor, bucket, bcode);
  k_dw_part<<<Ttok / CH, 512, 0, stream>>>(x, bucket, bcode, dw);
  finalize_cb<<<(Nn * Dd / 4) / 256, 256, 0, stream>>>(ema, dw, counts, hist, cbnew);
  quant_loss<<<2048, 256, 0, stream>>>(x, cbnew, idxb, q_out, loss, counter, loss_out);
}

// Round 6
// 126.525 us; speedup vs baseline: 1.3184x; 1.3184x over previous
//
#include <hip/hip_runtime.h>
#include <hip/hip_bf16.h>

constexpr int Dd   = 512;
constexpr int Nn   = 1024;
constexpr int Ttok = 16384;              // B*L
constexpr float DECAYc = 0.99f;
constexpr float MARGIN = 10.0f;
constexpr int CH = 16;                   // tokens per dw chunk

typedef short bf16x8 __attribute__((ext_vector_type(8)));
typedef float f32x4  __attribute__((ext_vector_type(4)));
typedef unsigned short us8v __attribute__((ext_vector_type(8)));

__device__ inline unsigned short f2bf(float f) {       // round-to-nearest-even
  unsigned int b = __float_as_uint(f);
  return (unsigned short)((b + 0x7FFFu + ((b >> 16) & 1u)) >> 16);
}
__device__ inline float bf2f(unsigned short u) {
  return __uint_as_float(((unsigned int)u) << 16);
}

// ------------------------------------------- codebook -> bf16, plus csq[n]
__global__ __launch_bounds__(64) void k_prep_cb(const float* __restrict__ cb,
                                                unsigned short* __restrict__ cbh,
                                                float* __restrict__ csq) {
  const int n = blockIdx.x, l = threadIdx.x;
  const float4* r = (const float4*)(cb + (size_t)n * Dd);
  float4 a = r[l], b = r[l + 64];
  float ss = a.x*a.x + a.y*a.y + a.z*a.z + a.w*a.w
           + b.x*b.x + b.y*b.y + b.z*b.z + b.w*b.w;
  ushort4 ua, ub;
  ua.x = f2bf(a.x); ua.y = f2bf(a.y); ua.z = f2bf(a.z); ua.w = f2bf(a.w);
  ub.x = f2bf(b.x); ub.y = f2bf(b.y); ub.z = f2bf(b.z); ub.w = f2bf(b.w);
  ((ushort4*)(cbh + (size_t)n * Dd))[l]      = ua;
  ((ushort4*)(cbh + (size_t)n * Dd))[l + 64] = ub;
#pragma unroll
  for (int o = 32; o; o >>= 1) ss += __shfl_down(ss, o);
  if (l == 0) csq[n] = ss;
}

// ---------------------- MFMA coarse-score GEMM: S[t][n] = csq[n] - 2*x.c
// LDS tiles XOR-swizzled (chunk' = chunk ^ (row&7), 16B chunks). A: swizzle
// via pre-swizzled GLOBAL source (global_load_lds dest stays linear);
// B: reg-staged, swizzled ds_write. Next B-tile prefetched under MFMA.
__global__ __launch_bounds__(256) void k_gemm_scores(
    const unsigned short* __restrict__ cbh, const float* __restrict__ x,
    const float* __restrict__ csq, unsigned short* __restrict__ S) {
  __shared__ unsigned short As[128 * 64];    // codes
  __shared__ unsigned short Bs[128 * 64];    // tokens
  const int tid = threadIdx.x;
  const int w = tid >> 6, l = tid & 63;
  const int b = blockIdx.x;
  const int s = (b & 7) * 128 + (b >> 3);    // XCD-aware bijective swizzle
  const int cm = s & 7;        // code-block  (M)
  const int tn = s >> 3;       // token-block (N)
  const int wr = w >> 1, wc = w & 1;

  const int srow = tid >> 3;                 // 0..31 staging row base
  const int xorw = (tid >> 3) & 7;           // row&7 of this thread's staged rows
  const int scolA = ((tid & 7) ^ xorw) * 8;  // A: swizzled global source chunk
  const int scolB = (tid & 7) * 8;           // B: linear global chunk
  const int wcolB = ((tid & 7) ^ xorw) * 8;  // B: swizzled LDS write chunk

  f32x4 acc[4][4] = {};

  const unsigned short* gA0 = cbh + (size_t)(cm * 128) * Dd;
  const float*          gB0 = x   + (size_t)(tn * 128) * Dd;

  us8v bq[4];
#define LOADB(KC) do {                                                        \
    const int k0_ = (KC) * 64;                                                \
    _Pragma("unroll")                                                         \
    for (int p = 0; p < 4; ++p) {                                             \
      const float* gb = gB0 + (size_t)(p * 32 + srow) * Dd + k0_ + scolB;     \
      float4 v0 = *(const float4*)gb;                                         \
      float4 v1 = *(const float4*)(gb + 4);                                   \
      us8v o;                                                                 \
      o[0]=f2bf(v0.x); o[1]=f2bf(v0.y); o[2]=f2bf(v0.z); o[3]=f2bf(v0.w);     \
      o[4]=f2bf(v1.x); o[5]=f2bf(v1.y); o[6]=f2bf(v1.z); o[7]=f2bf(v1.w);     \
      bq[p] = o;                                                              \
    }                                                                         \
  } while (0)

  LOADB(0);

  for (int kc = 0; kc < Dd / 64; ++kc) {
    const int k0 = kc * 64;
    __syncthreads();                      // previous tile fully consumed
#pragma unroll
    for (int c = 0; c < 4; ++c) {
      const unsigned short* ga = gA0 + (size_t)(c * 32 + srow) * Dd + k0 + scolA;
      char* la = (char*)As + c * 4096 + w * 1024;   // wave-uniform base, linear dest
      __builtin_amdgcn_global_load_lds((const __attribute__((address_space(1))) void*)ga,
                                       (__attribute__((address_space(3))) void*)la, 16, 0, 0);
    }
#pragma unroll
    for (int p = 0; p < 4; ++p)
      *(us8v*)&Bs[(p * 32 + srow) * 64 + wcolB] = bq[p];
    __syncthreads();                      // drains vmcnt+lgkmcnt
    if (kc + 1 < Dd / 64) LOADB(kc + 1);  // prefetch hides under MFMA
#pragma unroll
    for (int ks = 0; ks < 2; ++ks) {
      const int ra = l & 15;
      const int rx = l & 7;               // row&7 of the fragment rows
      const int kbs = ((ks * 4 + (l >> 4)) ^ rx) * 8;   // swizzled read chunk
      bf16x8 af[4], bfr[4];
#pragma unroll
      for (int m = 0; m < 4; ++m)
        af[m] = *(const bf16x8*)&As[(wr * 64 + m * 16 + ra) * 64 + kbs];
#pragma unroll
      for (int n = 0; n < 4; ++n)
        bfr[n] = *(const bf16x8*)&Bs[(wc * 64 + n * 16 + ra) * 64 + kbs];
#pragma unroll
      for (int m = 0; m < 4; ++m)
#pragma unroll
        for (int n = 0; n < 4; ++n)
          acc[m][n] = __builtin_amdgcn_mfma_f32_16x16x32_bf16(af[m], bfr[n], acc[m][n], 0, 0, 0);
    }
  }
#undef LOADB

  const int code0 = cm * 128 + wr * 64 + (l >> 4) * 4;
  const int tok0  = tn * 128 + wc * 64 + (l & 15);
#pragma unroll
  for (int m = 0; m < 4; ++m) {
    const int cd = code0 + m * 16;
    float4 cs = *(const float4*)&csq[cd];
#pragma unroll
    for (int n = 0; n < 4; ++n) {
      const int tk = tok0 + n * 16;
      ushort4 o;
      o.x = f2bf(cs.x - 2.0f * acc[m][n][0]);
      o.y = f2bf(cs.y - 2.0f * acc[m][n][1]);
      o.z = f2bf(cs.z - 2.0f * acc[m][n][2]);
      o.w = f2bf(cs.w - 2.0f * acc[m][n][3]);
      *(ushort4*)(S + (size_t)tk * Nn + cd) = o;
    }
  }
}

// ------------- per-token: coarse min over 1024, candidates, exact rescore
__global__ __launch_bounds__(256) void k_scan(
    const unsigned short* __restrict__ S, const float* __restrict__ x,
    const float* __restrict__ cb, const float* __restrict__ csq,
    int* __restrict__ idxb, float* __restrict__ idxf, float* __restrict__ hist) {
  __shared__ int candn[4][32];
  __shared__ int ccnt[4];
  const int tid = threadIdx.x, wid = tid >> 6, l = tid & 63;
  const int t = blockIdx.x * 4 + wid;

  const unsigned short* row = S + (size_t)t * Nn;
  us8v c0 = *(const us8v*)(row + l * 8);
  us8v c1 = *(const us8v*)(row + 512 + l * 8);
  float f0[8], f1[8];
  float minv = 3.4e38f; int mini = 0;
#pragma unroll
  for (int j = 0; j < 8; ++j) {
    f0[j] = bf2f(c0[j]);
    if (f0[j] < minv) { minv = f0[j]; mini = l * 8 + j; }
  }
#pragma unroll
  for (int j = 0; j < 8; ++j) {
    f1[j] = bf2f(c1[j]);
    if (f1[j] < minv) { minv = f1[j]; mini = 512 + l * 8 + j; }
  }
#pragma unroll
  for (int o = 1; o < 64; o <<= 1) {
    float ov = __shfl_xor(minv, o); int oi = __shfl_xor(mini, o);
    if (ov < minv || (ov == minv && oi < mini)) { minv = ov; mini = oi; }
  }
  if (l == 0) ccnt[wid] = 0;
  const float thr = minv + MARGIN;
#pragma unroll
  for (int j = 0; j < 8; ++j)
    if (f0[j] <= thr) { int p = atomicAdd(&ccnt[wid], 1); if (p < 32) candn[wid][p] = l * 8 + j; }
#pragma unroll
  for (int j = 0; j < 8; ++j)
    if (f1[j] <= thr) { int p = atomicAdd(&ccnt[wid], 1); if (p < 32) candn[wid][p] = 512 + l * 8 + j; }
  int nc = ccnt[wid]; if (nc > 32) nc = 32;

  int besti;
  if (nc == 1) {
    besti = candn[wid][0];
  } else {
    float bestv = 3.4e38f; besti = 0x7fffffff;
    const float4* xr = (const float4*)(x + (size_t)t * Dd);
    float4 xa = xr[l * 2], xb = xr[l * 2 + 1];
    for (int c = 0; c < nc; ++c) {
      int n = candn[wid][c];
      const float4* cr = (const float4*)(cb + (size_t)n * Dd);
      float4 ca = cr[l * 2], cb4 = cr[l * 2 + 1];
      float p = xa.x*ca.x + xa.y*ca.y + xa.z*ca.z + xa.w*ca.w
              + xb.x*cb4.x + xb.y*cb4.y + xb.z*cb4.z + xb.w*cb4.w;
#pragma unroll
      for (int o = 32; o; o >>= 1) p += __shfl_xor(p, o);
      float sc = csq[n] - 2.0f * p;
      if (sc < bestv || (sc == bestv && n < besti)) { bestv = sc; besti = n; }
    }
  }
  if (l == 0) {
    idxb[t] = besti;
    idxf[t] = (float)besti;
    atomicAdd(&hist[besti], 1.0f);
  }
}

// ----------------- prefix sum of histogram (1 block, 256 thr, wave scan)
__global__ __launch_bounds__(256) void k_offsets(const float* __restrict__ hist,
                                                 int* __restrict__ offs,
                                                 int* __restrict__ cursor) {
  __shared__ int wsum[4];
  const int tid = threadIdx.x, l = tid & 63, wd = tid >> 6;
  const int base = tid * 4;
  int c0 = (int)hist[base], c1 = (int)hist[base + 1],
      c2 = (int)hist[base + 2], c3 = (int)hist[base + 3];
  int sum = c0 + c1 + c2 + c3;
  int sc = sum;
#pragma unroll
  for (int o = 1; o < 64; o <<= 1) { int v = __shfl_up(sc, o); if (l >= o) sc += v; }
  if (l == 63) wsum[wd] = sc;
  __syncthreads();
  int wbase = 0;
  for (int i = 0; i < wd; ++i) wbase += wsum[i];
  int e = wbase + sc - sum;                 // exclusive prefix for this group
  offs[base] = e;     cursor[base] = e;
  offs[base+1] = e + c0; cursor[base+1] = e + c0;
  offs[base+2] = e + c0 + c1; cursor[base+2] = e + c0 + c1;
  offs[base+3] = e + c0 + c1 + c2; cursor[base+3] = e + c0 + c1 + c2;
}

// -------------------------------- bucket tokens by index (code-sorted order)
__global__ __launch_bounds__(256) void k_scatter(const int* __restrict__ idxb,
                                                 int* __restrict__ cursor,
                                                 int* __restrict__ bucket,
                                                 int* __restrict__ bcode) {
  int t = blockIdx.x * 256 + threadIdx.x;
  if (t < Ttok) {
    int n = idxb[t];
    int p = atomicAdd(&cursor[n], 1);
    bucket[p] = t;
    bcode[p] = n;
  }
}

// ------- load-balanced segmented sum: dw[n][d] += x rows of chunk segments
__global__ __launch_bounds__(512) void k_dw_part(
    const float* __restrict__ x, const int* __restrict__ bucket,
    const int* __restrict__ bcode, float* __restrict__ dw) {
  __shared__ int sh_t[CH], sh_n[CH];
  const int tid = threadIdx.x;
  const int p0 = blockIdx.x * CH;
  if (tid < CH) { sh_t[tid] = bucket[p0 + tid]; sh_n[tid] = bcode[p0 + tid]; }
  __syncthreads();
  float v[CH];
#pragma unroll
  for (int j = 0; j < CH; ++j)
    v[j] = x[(size_t)sh_t[j] * Dd + tid];    // 16 independent loads in flight
  float acc = v[0]; int cur = sh_n[0];       // segmented accumulate (uniform branch)
#pragma unroll
  for (int j = 1; j < CH; ++j) {
    int n = sh_n[j];
    if (n != cur) { atomicAdd(&dw[(size_t)cur * Dd + tid], acc); acc = 0.f; cur = n; }
    acc += v[j];
  }
  atomicAdd(&dw[(size_t)cur * Dd + tid], acc);
}

// -------- codebook_new = (decay*ema + (1-decay)*dw) / (decay*counts + (1-decay)*hist)
__global__ __launch_bounds__(256) void finalize_cb(
    const float* __restrict__ ema, const float* __restrict__ dw,
    const float* __restrict__ counts, const float* __restrict__ hist,
    float* __restrict__ cbnew) {
  int e4 = blockIdx.x * 256 + threadIdx.x;   // float4 index
  int n = e4 >> 7;
  float cnt = DECAYc * counts[n] + (1.0f - DECAYc) * hist[n];
  float inv = 1.0f / cnt;
  float4 e = ((const float4*)ema)[e4];
  float4 d = ((const float4*)dw)[e4];
  float4 o;
  o.x = (DECAYc * e.x + (1.0f - DECAYc) * d.x) * inv;
  o.y = (DECAYc * e.y + (1.0f - DECAYc) * d.y) * inv;
  o.z = (DECAYc * e.z + (1.0f - DECAYc) * d.z) * inv;
  o.w = (DECAYc * e.w + (1.0f - DECAYc) * d.w) * inv;
  ((float4*)cbnew)[e4] = o;
}

// ------- quantized = gather(cbnew, idx); loss partials. 4 independent
// float4s per thread (manually unrolled -> loads all in flight, ILP-bound
// fix for the 1.2 TB/s latency limit seen in r4/r5 counters).
__global__ __launch_bounds__(256) void quant_loss(
    const float* __restrict__ x, const float* __restrict__ cbnew,
    const int* __restrict__ idx, float* __restrict__ out_q,
    float* __restrict__ loss) {
  const int e0 = blockIdx.x * 256 + threadIdx.x;
  const int gsz = 524288;                    // 2048 blocks * 256 threads
  int n[4]; float4 q[4], xv[4];
#pragma unroll
  for (int j = 0; j < 4; ++j) n[j] = idx[(e0 + j * gsz) >> 7];
#pragma unroll
  for (int j = 0; j < 4; ++j) {
    const int e = e0 + j * gsz;
    q[j]  = ((const float4*)(cbnew + (size_t)n[j] * Dd))[e & 127];
    xv[j] = ((const float4*)x)[e];
  }
  float part = 0.f;
#pragma unroll
  for (int j = 0; j < 4; ++j) {
    ((float4*)out_q)[e0 + j * gsz] = q[j];
    float dx = xv[j].x - q[j].x, dy = xv[j].y - q[j].y,
          dz = xv[j].z - q[j].z, dw_ = xv[j].w - q[j].w;
    part += dx*dx + dy*dy + dz*dz + dw_*dw_;
  }
  __shared__ float red[4];
#pragma unroll
  for (int o = 32; o; o >>= 1) part += __shfl_down(part, o);
  int wid = threadIdx.x >> 6, lane = threadIdx.x & 63;
  if (lane == 0) red[wid] = part;
  __syncthreads();
  if (threadIdx.x == 0) atomicAdd(loss, red[0] + red[1] + red[2] + red[3]);
}

__global__ void loss_final(const float* __restrict__ loss,
                           float* __restrict__ out_loss) {
  *out_loss = loss[0] * (0.5f / (float)((size_t)Ttok * Dd));
}

// ---------------------------------------------------------------- launch
extern "C" void kernel_launch(void* const* d_in, const int* in_sizes, int n_in,
                              void* d_out, int out_size, void* d_ws, size_t ws_size,
                              hipStream_t stream) {
  const float* x      = (const float*)d_in[0];
  const float* cb     = (const float*)d_in[1];
  const float* ema    = (const float*)d_in[2];
  const float* counts = (const float*)d_in[3];

  float* out      = (float*)d_out;
  float* q_out    = out;
  float* loss_out = out + (size_t)Ttok * Dd;
  float* idxf_out = loss_out + 1;
  // coarse score matrix S (bf16 [16384][1024] = 33.5 MB) aliases q_out;
  // fully consumed by k_scan before quant_loss overwrites it.
  unsigned short* S = (unsigned short*)q_out;

  // workspace layout (float offsets)
  float* ws = (float*)d_ws;
  unsigned short* cbh = (unsigned short*)ws;           // [0, 262144)  bf16 cb
  float* dw      = ws + 262144;                        // 524288 (zeroed)
  float* hist    = ws + 786432;                        // 1024   (zeroed)
  float* loss    = ws + 787456;                        // 4      (zeroed)
  float* csq     = ws + 787460;                        // 1024
  int*   offs    = (int*)(ws + 788484);                // 1024
  int*   cursor  = (int*)(ws + 789508);                // 1024
  int*   bucket  = (int*)(ws + 790532);                // 16384
  int*   bcode   = (int*)(ws + 806916);                // 16384
  int*   idxb    = (int*)(ws + 823300);                // 16384
  float* cbnew   = ws + 839684;                        // 524288 -> ends 1363972
  // total 1,363,972 floats = 5.46 MB

  // zero dw + hist + loss (contiguous) every call
  hipMemsetAsync(dw, 0, (size_t)525316 * sizeof(float), stream);

  k_prep_cb<<<Nn, 64, 0, stream>>>(cb, cbh, csq);
  k_gemm_scores<<<(Nn / 128) * (Ttok / 128), 256, 0, stream>>>(cbh, x, csq, S);
  k_scan<<<Ttok / 4, 256, 0, stream>>>(S, x, cb, csq, idxb, idxf_out, hist);
  k_offsets<<<1, 256, 0, stream>>>(hist, offs, cursor);
  k_scatter<<<Ttok / 256, 256, 0, stream>>>(idxb, cursor, bucket, bcode);
  k_dw_part<<<Ttok / CH, 512, 0, stream>>>(x, bucket, bcode, dw);
  finalize_cb<<<(Nn * Dd / 4) / 256, 256, 0, stream>>>(ema, dw, counts, hist, cbnew);
  quant_loss<<<2048, 256, 0, stream>>>(x, cbnew, idxb, q_out, loss);
  loss_final<<<1, 1, 0, stream>>>(loss, loss_out);
}